// Round 5
// baseline (196.489 us; speedup 1.0000x reference)
//
#include <hip/hip_runtime.h>
#include <hip/hip_bf16.h>

// TopPool: out[b,c,h,w] = max_{h'>=h} x[b,c,h',w]  (reverse cummax over axis 2)
// x shape (32, 256, 128, 128) fp32, w innermost.
// One thread per (plane, w4) column. Compulsory traffic 0.537+0.537 GB.
// 2-deep software pipeline (prefetch next batch before current batch's chain).
// R5 tweaks: ascending-address order within every batch (loads, stores), and
// stores issued as a separate burst AFTER the fmax chain (tmp[] staging) so
// the DRAM controller sees 4KB ascending read bursts and 4KB ascending write
// bursts instead of fine-grained descending read/write interleave.

#define H 128
#define W4 32   // 128 floats / 4 per float4
#define U 8     // h-steps per batch
#define NB (H / U)  // 16 batches

typedef float f32x4 __attribute__((ext_vector_type(4)));

__device__ __forceinline__ f32x4 fmax4(f32x4 a, f32x4 b) {
    f32x4 r;
    r.x = fmaxf(a.x, b.x);
    r.y = fmaxf(a.y, b.y);
    r.z = fmaxf(a.z, b.z);
    r.w = fmaxf(a.w, b.w);
    return r;
}

__global__ __launch_bounds__(256) void toppool_kernel(const f32x4* __restrict__ x,
                                                      f32x4* __restrict__ out) {
    const int tid   = blockIdx.x * blockDim.x + threadIdx.x;   // 0 .. 262143
    const int w4    = tid & (W4 - 1);
    const int plane = tid >> 5;                                 // b*C + c

    const size_t base = (size_t)plane * H * W4 + w4;
    const f32x4* xp = x + base;
    f32x4* op = out + base;

    // cur[i] holds x at h = hlo + i  (ascending within batch)
    f32x4 cur[U], nxt[U], tmp[U];

    // prologue: batch 0 is h in [H-U, H-1]; load ascending
    #pragma unroll
    for (int i = 0; i < U; ++i)
        cur[i] = __builtin_nontemporal_load(&xp[(H - U + i) * W4]);

    f32x4 m;
    m.x = -__builtin_huge_valf();
    m.y = -__builtin_huge_valf();
    m.z = -__builtin_huge_valf();
    m.w = -__builtin_huge_valf();

    // batches descend; everything inside a batch ascends in address
    for (int b = 0; b < NB - 1; ++b) {
        const int hlo = H - (b + 1) * U;        // low h of current batch
        // prefetch next (lower) batch, ascending addresses
        #pragma unroll
        for (int i = 0; i < U; ++i)
            nxt[i] = __builtin_nontemporal_load(&xp[(hlo - U + i) * W4]);
        // fmax chain: logical order is descending h (suffix max), register-only
        #pragma unroll
        for (int i = U - 1; i >= 0; --i) {
            m = fmax4(m, cur[i]);
            tmp[i] = m;
        }
        // store burst, ascending addresses
        #pragma unroll
        for (int i = 0; i < U; ++i)
            __builtin_nontemporal_store(tmp[i], &op[(hlo + i) * W4]);
        #pragma unroll
        for (int i = 0; i < U; ++i) cur[i] = nxt[i];
    }

    // epilogue: last batch, h in [0, U-1]
    #pragma unroll
    for (int i = U - 1; i >= 0; --i) {
        m = fmax4(m, cur[i]);
        tmp[i] = m;
    }
    #pragma unroll
    for (int i = 0; i < U; ++i)
        __builtin_nontemporal_store(tmp[i], &op[i * W4]);
}

extern "C" void kernel_launch(void* const* d_in, const int* in_sizes, int n_in,
                              void* d_out, int out_size, void* d_ws, size_t ws_size,
                              hipStream_t stream) {
    const f32x4* x = (const f32x4*)d_in[0];
    f32x4* out = (f32x4*)d_out;

    const int total = 32 * 256 * W4;   // 262144 threads
    const int block = 256;
    const int grid = total / block;    // 1024
    toppool_kernel<<<grid, block, 0, stream>>>(x, out);
}